// Round 15
// baseline (220.271 us; speedup 1.0000x reference)
//
#include <hip/hip_runtime.h>
#include <hip/hip_bf16.h>
#include <math.h>

#define Tt 4096
#define Dd 1024
#define Ff 2048
#define Ee 8

typedef unsigned short u16;
typedef short bf16x8 __attribute__((ext_vector_type(8)));
typedef float f32x4 __attribute__((ext_vector_type(4)));

__device__ __forceinline__ u16 f2bf(float f) {
  union { float f; unsigned u; } v; v.f = f;
  unsigned r = v.u + 0x7fffu + ((v.u >> 16) & 1u);
  return (u16)(r >> 16);
}

// async global->LDS, 16B per lane; LDS dest = wave-uniform base + lane*16
__device__ __forceinline__ void gload16(const void* g, void* l) {
  __builtin_amdgcn_global_load_lds(
      (const __attribute__((address_space(1))) unsigned int*)g,
      (__attribute__((address_space(3))) unsigned int*)l, 16, 0, 0);
}

// ---------------- shared device pieces ----------------
__device__ __forceinline__ void router_body(
    int t, int tid, const float* __restrict__ x, const float* __restrict__ gw,
    float* __restrict__ logits, u16* __restrict__ xb)
{
  int lane = tid & 63;
  const float* xr = x + (size_t)t * Dd;
  float xv[16];
#pragma unroll
  for (int i = 0; i < 4; ++i) {
    float4 v = *reinterpret_cast<const float4*>(xr + lane * 16 + i * 4);
    xv[i*4+0] = v.x; xv[i*4+1] = v.y; xv[i*4+2] = v.z; xv[i*4+3] = v.w;
  }
  if (xb) {
#pragma unroll
    for (int i = 0; i < 4; ++i) {
      ushort4 b;
      b.x = f2bf(xv[i*4+0]); b.y = f2bf(xv[i*4+1]);
      b.z = f2bf(xv[i*4+2]); b.w = f2bf(xv[i*4+3]);
      *reinterpret_cast<ushort4*>(xb + (size_t)t * Dd + lane * 16 + i * 4) = b;
    }
  }
#pragma unroll
  for (int e = 0; e < Ee; ++e) {
    const float* gr = gw + (size_t)e * Dd + lane * 16;
    float s = 0.f;
#pragma unroll
    for (int i = 0; i < 4; ++i) {
      float4 g = *reinterpret_cast<const float4*>(gr + i * 4);
      s += xv[i*4+0]*g.x + xv[i*4+1]*g.y + xv[i*4+2]*g.z + xv[i*4+3]*g.w;
    }
#pragma unroll
    for (int o = 32; o > 0; o >>= 1) s += __shfl_xor(s, o);
    if (lane == 0) logits[(size_t)t * Ee + e] = s;
  }
}

__device__ __forceinline__ void transpose_tile(
    const float* __restrict__ ip, u16* __restrict__ op, int R, int C,
    int r0, int c0, int tid, u16 st[][65])
{
  int rr = tid >> 2;
  int cb = (tid & 3) * 16;
#pragma unroll
  for (int i = 0; i < 4; ++i) {
    float4 v = *reinterpret_cast<const float4*>(ip + (size_t)(r0 + rr) * C + c0 + cb + i * 4);
    st[rr][cb + i*4 + 0] = f2bf(v.x);
    st[rr][cb + i*4 + 1] = f2bf(v.y);
    st[rr][cb + i*4 + 2] = f2bf(v.z);
    st[rr][cb + i*4 + 3] = f2bf(v.w);
  }
  __syncthreads();
#pragma unroll
  for (int i = 0; i < 4; ++i) {
    ushort4 b;
    b.x = st[cb + i*4 + 0][rr];
    b.y = st[cb + i*4 + 1][rr];
    b.z = st[cb + i*4 + 2][rr];
    b.w = st[cb + i*4 + 3][rr];
    *reinterpret_cast<ushort4*>(op + (size_t)(c0 + rr) * R + r0 + cb + i * 4) = b;
  }
}

// r10 GEMM body + KSPLIT: 128x128 tile, 4 waves, 3-buffer counted-vmcnt
// pipeline, piece-slot XOR swizzle (0 bank conflicts), expert-pinned XCD
// chunking (both K-halves of expert e on XCD e).
// MODE 0: h1[slot] = silu(xb[list[slot]] @ w1T[e]^T)
// MODE 1: out[list[slot]] += wgt[slot]*(h1[slot] @ w2T[e]^T)  (atomicAdd)
template<int MODE, int N_, int K_, int KSPLIT>
__device__ __forceinline__ void gemm_body(
    int orig, u16* __restrict__ Al, u16* __restrict__ Bl,
    const u16* __restrict__ Abase, const u16* __restrict__ Bbase,
    void* __restrict__ Cout, const int* __restrict__ meta,
    const int* __restrict__ list, const float* __restrict__ wgt)
{
  constexpr int NXc = N_ / 128;
  constexpr int NYc = 32;               // covers worst-case cnt=4096
  constexpr int CPX = NXc * NYc * KSPLIT;
  constexpr int ABUF = 128 * 32;        // u16 per buffer (8 KB)
  constexpr int KLOC = K_ / KSPLIT;
  constexpr int NT  = KLOC / 32;

  const int swz  = (orig & 7) * CPX + (orig >> 3);
  const int bz   = swz / (NXc * NYc);
  const int rem  = swz - bz * (NXc * NYc);
  const int by   = rem / NXc;
  const int bx   = rem - by * NXc;

  const int e   = bz / KSPLIT;          // consecutive bz = same expert -> same XCD
  const int kh  = bz - e * KSPLIT;
  const int cnt = meta[e];
  if (by * 128 >= cnt) return;
  const int off = meta[32 + e];
  const int kbase = kh * KLOC;

  const int tid  = threadIdx.x;
  const int lane = tid & 63;
  const int wave = tid >> 6;
  const int wr   = wave >> 1, wc = wave & 1;
  const int n0   = bx * 128;

  const int l4 = lane >> 2;
  const int kp = (((lane & 3) ^ ((lane >> 3) & 3))) * 8;   // swizzled k-piece (shorts)

  const u16* aptr[2];
  int aoff[2];
#pragma unroll
  for (int c = 0; c < 2; ++c) {
    int chunk = wave * 2 + c;
    int row = chunk * 16 + l4;
    int i = by * 128 + row;
    if (i >= cnt) i = cnt - 1;          // clamp tail (dup rows; epilogue guards)
    int srow = (MODE == 0) ? list[off + i] : (off + i);
    aptr[c] = Abase + (size_t)srow * K_ + kbase + kp;
    aoff[c] = chunk * 512;
  }
  const u16* bptr[2];
  int boff[2];
#pragma unroll
  for (int c = 0; c < 2; ++c) {
    int chunk = wave * 2 + c;
    int row = chunk * 16 + l4;
    bptr[c] = Bbase + ((size_t)e * N_ + n0 + row) * K_ + kbase + kp;
    boff[c] = chunk * 512;
  }

  f32x4 acc[4][4] = {};
  const int r16 = lane & 15;
  const int kqs = (((lane >> 4) ^ ((lane >> 1) & 3))) * 8; // swizzled read slot

  u16 *a0 = Al, *a1 = Al + ABUF, *a2 = Al + 2 * ABUF;
  u16 *b0 = Bl, *b1 = Bl + ABUF, *b2 = Bl + 2 * ABUF;

  // prologue: stage tile 0 -> buf0, tile 1 -> buf1 (8 loads in flight per wave)
#pragma unroll
  for (int c = 0; c < 2; ++c) { gload16(aptr[c], a0 + aoff[c]); gload16(bptr[c], b0 + boff[c]); }
#pragma unroll
  for (int c = 0; c < 2; ++c) { gload16(aptr[c] + 32, a1 + aoff[c]); gload16(bptr[c] + 32, b1 + boff[c]); }

  for (int t = 0; t < NT; ++t) {
    if (t + 1 < NT) asm volatile("s_waitcnt vmcnt(4)" ::: "memory");
    else            asm volatile("s_waitcnt vmcnt(0)" ::: "memory");
    __builtin_amdgcn_s_barrier();           // tile t visible to all waves

    if (t + 2 < NT) {                       // prefetch t+2 into the spare buffer
      int k0 = (t + 2) * 32;
#pragma unroll
      for (int c = 0; c < 2; ++c) { gload16(aptr[c] + k0, a2 + aoff[c]); gload16(bptr[c] + k0, b2 + boff[c]); }
    }

    bf16x8 af[4], bfv[4];
#pragma unroll
    for (int m = 0; m < 4; ++m)
      af[m] = *reinterpret_cast<const bf16x8*>(&a0[(wr*64 + m*16 + r16) * 32 + kqs]);
#pragma unroll
    for (int n = 0; n < 4; ++n)
      bfv[n] = *reinterpret_cast<const bf16x8*>(&b0[(wc*64 + n*16 + r16) * 32 + kqs]);
    __builtin_amdgcn_s_setprio(1);
#pragma unroll
    for (int m = 0; m < 4; ++m)
#pragma unroll
      for (int n = 0; n < 4; ++n)
        acc[m][n] = __builtin_amdgcn_mfma_f32_16x16x32_bf16(af[m], bfv[n], acc[m][n], 0, 0, 0);
    __builtin_amdgcn_s_setprio(0);

    u16* ta = a0; a0 = a1; a1 = a2; a2 = ta;   // rotate buffers
    u16* tb = b0; b0 = b1; b1 = b2; b2 = tb;
  }

  // epilogue: C/D frag layout col=lane&15, row=(lane>>4)*4+reg
  const int colb = n0 + wc * 64 + r16;
  const int rb4  = wr * 64 + ((lane >> 4) << 2);
#pragma unroll
  for (int m = 0; m < 4; ++m) {
#pragma unroll
    for (int r = 0; r < 4; ++r) {
      int i = by * 128 + rb4 + m * 16 + r;
      if (i >= cnt) continue;
      if (MODE == 0) {
        u16* hp = (u16*)Cout + (size_t)(off + i) * N_;
#pragma unroll
        for (int n = 0; n < 4; ++n) {
          float v = acc[m][n][r];
          v = v / (1.f + expf(-v));            // silu
          hp[colb + n * 16] = f2bf(v);
        }
      } else {
        int   tok = list[off + i];
        float w   = wgt[off + i];
        float* o = (float*)Cout + (size_t)tok * N_;
#pragma unroll
        for (int n = 0; n < 4; ++n)
          atomicAdd(&o[colb + n * 16], w * acc[m][n][r]);
      }
    }
  }
}

// ---------------- standalone kernels ----------------
__global__ __launch_bounds__(256) void router_kernel(
    const float* __restrict__ x, const float* __restrict__ gw,
    float* __restrict__ logits, u16* __restrict__ xb)
{
  router_body(blockIdx.x * 4 + (threadIdx.x >> 6), threadIdx.x, x, gw, logits, xb);
}

// FUSE1: blocks [0,4096) transpose w1 [Dd][Ff]->w1T [Ff][Dd] (expert-pinned);
//        blocks [4096,5120) router (writes logits + xb). Disjoint outputs.
__global__ __launch_bounds__(256) void fuse1_kernel(
    const float* __restrict__ x, const float* __restrict__ gw,
    float* __restrict__ logits, u16* __restrict__ xb,
    const float* __restrict__ w1, u16* __restrict__ w1T)
{
  __shared__ u16 st[64][65];
  const int orig = blockIdx.x;
  if (orig < 4096) {
    int swz = (orig & 7) * 512 + (orig >> 3);
    int e   = swz / 512;                   // expert e -> XCD e (matches GEMM pinning)
    int rem = swz - e * 512;
    int by  = rem / 32, bx = rem - (rem / 32) * 32;
    const size_t eo = (size_t)e * Dd * Ff;
    transpose_tile(w1 + eo, w1T + eo, Dd, Ff, by * 64, bx * 64, threadIdx.x, st);
  } else {
    router_body((orig - 4096) * 4 + (threadIdx.x >> 6), threadIdx.x, x, gw, logits, xb);
  }
}

// FUSE2: blocks [0,4096) = up-proj GEMM (reads w1T); blocks [4096,8192) =
// transpose w2 [Ff][Dd]->w2T [Dd][Ff] into a SEPARATE buffer. 48KB LDS pool
// shared so GEMM occupancy stays 3 blocks/CU.
__global__ __launch_bounds__(256) void fuse2_kernel(
    const u16* __restrict__ Abase, const u16* __restrict__ Bbase,
    void* __restrict__ Cout, const int* __restrict__ meta,
    const int* __restrict__ list, const float* __restrict__ wgt,
    const float* __restrict__ w2, u16* __restrict__ w2T)
{
  constexpr int ABUF = 128 * 32;
  __shared__ u16 pool[6 * ABUF];           // 48 KB
  const int orig = blockIdx.x;
  if (orig < 4096) {
    gemm_body<0, Ff, Dd, 1>(orig, pool, pool + 3 * ABUF, Abase, Bbase, Cout, meta, list, wgt);
  } else {
    int og  = orig - 4096;
    int swz = (og & 7) * 512 + (og >> 3);
    int e   = swz / 512;
    int rem = swz - e * 512;
    int byy = rem / 16, bxx = rem - (rem / 16) * 16;
    const size_t eo = (size_t)e * Ff * Dd;
    transpose_tile(w2 + eo, w2T + eo, Ff, Dd, byy * 64, bxx * 64, threadIdx.x,
                   reinterpret_cast<u16(*)[65]>(pool));
  }
}

template<int MODE, int N_, int K_, int KSPLIT>
__global__ __launch_bounds__(256) void gemm_g(
    const u16* __restrict__ Abase, const u16* __restrict__ Bbase,
    void* __restrict__ Cout, const int* __restrict__ meta,
    const int* __restrict__ list, const float* __restrict__ wgt)
{
  constexpr int ABUF = 128 * 32;
  __shared__ u16 Al[3 * ABUF];
  __shared__ u16 Bl[3 * ABUF];
  const int orig = blockIdx.x + (N_ / 128) * (blockIdx.y + 32 * blockIdx.z);
  gemm_body<MODE, N_, K_, KSPLIT>(orig, Al, Bl, Abase, Bbase, Cout, meta, list, wgt);
}

// transpose [R][C] f32 -> [C][R] bf16, per expert (blockIdx.z) — serial path
__global__ __launch_bounds__(256) void transpose_bf16_kernel(
    const float* __restrict__ in, u16* __restrict__ out, int R, int C)
{
  __shared__ u16 st[64][65];
  const size_t eoff = (size_t)blockIdx.z * R * C;
  transpose_tile(in + eoff, out + eoff, R, C, blockIdx.y * 64, blockIdx.x * 64,
                 threadIdx.x, st);
}

// ---------------- build: single block, 8 per-expert groups (r10) ----------------
__global__ __launch_bounds__(256) void build_kernel(
    const float* __restrict__ logits, int* __restrict__ meta,
    int* __restrict__ list, float* __restrict__ wgt)
{
  __shared__ int hist[8], cur[8];
  const int tid = threadIdx.x;
  const int lane = tid & 63;
  if (tid < 8) hist[tid] = 0;
  __syncthreads();
  for (int it = 0; it < Tt / 256; ++it) {
    int t = it * 256 + tid;
    float4 lo = *reinterpret_cast<const float4*>(logits + (size_t)t * 8);
    float4 hi = *reinterpret_cast<const float4*>(logits + (size_t)t * 8 + 4);
    float s[8] = {lo.x, lo.y, lo.z, lo.w, hi.x, hi.y, hi.z, hi.w};
    int i1 = 0; float m1 = s[0];
#pragma unroll
    for (int e = 1; e < 8; ++e) if (s[e] > m1) { m1 = s[e]; i1 = e; }
    int i2 = -1; float m2 = -__builtin_inff();
#pragma unroll
    for (int e = 0; e < 8; ++e) if (e != i1 && s[e] > m2) { m2 = s[e]; i2 = e; }
#pragma unroll
    for (int k = 0; k < 2; ++k) {
      int gg = k ? i2 : i1;
      unsigned long long m = ~0ull;
#pragma unroll
      for (int b = 0; b < 3; ++b) {
        unsigned long long vb = __ballot((gg >> b) & 1);
        m &= ((gg >> b) & 1) ? vb : ~vb;
      }
      int rank = __popcll(m & ((1ull << lane) - 1));
      if (rank == 0) atomicAdd(&hist[gg], __popcll(m));
    }
  }
  __syncthreads();
  if (tid == 0) {
    int sacc = 0;
    for (int g = 0; g < 8; ++g) {
      meta[g] = hist[g];
      meta[32 + g] = sacc;
      cur[g] = sacc;
      sacc += hist[g];
    }
  }
  __syncthreads();
  for (int it = 0; it < Tt / 256; ++it) {
    int t = it * 256 + tid;
    float4 lo = *reinterpret_cast<const float4*>(logits + (size_t)t * 8);
    float4 hi = *reinterpret_cast<const float4*>(logits + (size_t)t * 8 + 4);
    float s[8] = {lo.x, lo.y, lo.z, lo.w, hi.x, hi.y, hi.z, hi.w};
    int i1 = 0; float m1 = s[0];
#pragma unroll
    for (int e = 1; e < 8; ++e) if (s[e] > m1) { m1 = s[e]; i1 = e; }
    int i2 = -1; float m2 = -__builtin_inff();
#pragma unroll
    for (int e = 0; e < 8; ++e) if (e != i1 && s[e] > m2) { m2 = s[e]; i2 = e; }
    float wa = 1.f / (1.f + expf(m2 - m1));   // renormalized top-2 softmax
#pragma unroll
    for (int k = 0; k < 2; ++k) {
      int gg = k ? i2 : i1;
      float w = k ? (1.f - wa) : wa;
      unsigned long long m = ~0ull;
#pragma unroll
      for (int b = 0; b < 3; ++b) {
        unsigned long long vb = __ballot((gg >> b) & 1);
        m &= ((gg >> b) & 1) ? vb : ~vb;
      }
      int rank = __popcll(m & ((1ull << lane) - 1));
      int ldr = __ffsll(m) - 1;
      int base = 0;
      if (rank == 0) base = atomicAdd(&cur[gg], __popcll(m));
      base = __shfl(base, ldr);
      list[base + rank] = t;
      wgt[base + rank] = w;
    }
  }
}

// ---------------- dense fallback (small-ws path) ----------------
__global__ __launch_bounds__(256) void combine_kernel(
    const float* __restrict__ logits, float* __restrict__ combine)
{
  int t = blockIdx.x * 256 + threadIdx.x;
  if (t >= Tt) return;
  float4 lo = *reinterpret_cast<const float4*>(logits + (size_t)t * 8);
  float4 hi = *reinterpret_cast<const float4*>(logits + (size_t)t * 8 + 4);
  float s[8] = {lo.x, lo.y, lo.z, lo.w, hi.x, hi.y, hi.z, hi.w};
  int i1 = 0; float m1 = s[0];
#pragma unroll
  for (int e = 1; e < 8; ++e) if (s[e] > m1) { m1 = s[e]; i1 = e; }
  int i2 = -1; float m2 = -__builtin_inff();
#pragma unroll
  for (int e = 0; e < 8; ++e) if (e != i1 && s[e] > m2) { m2 = s[e]; i2 = e; }
  float wa = 1.f / (1.f + expf(m2 - m1));
#pragma unroll
  for (int e = 0; e < 8; ++e)
    combine[(size_t)t * 8 + e] = (e == i1) ? wa : ((e == i2) ? (1.f - wa) : 0.f);
}

template<int MODE, int N_, int K_>
__global__ __launch_bounds__(256) void gemm_dense(
    const float* __restrict__ A, const float* __restrict__ Bg,
    float* __restrict__ C, const float* __restrict__ combine,
    int expert, int first)
{
  constexpr int BM = 128, BN = 128, BK = 32, LDT = 40;
  __shared__ u16 Al[BM * LDT];
  __shared__ u16 Bl[BN * LDT];
  const int tid  = threadIdx.x;
  const int lane = tid & 63;
  const int wave = tid >> 6;
  const int wr = wave >> 1, wc = wave & 1;
  const int m0 = blockIdx.y * BM;
  const int n0 = blockIdx.x * BN;
  f32x4 acc[4][4] = {};
  for (int k0 = 0; k0 < K_; k0 += BK) {
#pragma unroll
    for (int i = 0; i < 4; ++i) {
      int f = tid + 256 * i;
      int row = f >> 3;
      int c4 = (f & 7) << 2;
      float4 v = *reinterpret_cast<const float4*>(A + (size_t)(m0 + row) * K_ + k0 + c4);
      ushort4 b;
      b.x = f2bf(v.x); b.y = f2bf(v.y); b.z = f2bf(v.z); b.w = f2bf(v.w);
      *reinterpret_cast<ushort4*>(&Al[row * LDT + c4]) = b;
    }
    {
      int n  = tid & 127;
      int kb = (tid >> 7) << 4;
      const float* bp = Bg + (size_t)(k0 + kb) * N_ + n0 + n;
      u16 tmp[16];
#pragma unroll
      for (int kk = 0; kk < 16; ++kk)
        tmp[kk] = f2bf(bp[(size_t)kk * N_]);
      u16* p = &Bl[n * LDT + kb];
#pragma unroll
      for (int i = 0; i < 4; ++i) {
        ushort4 b;
        b.x = tmp[i*4+0]; b.y = tmp[i*4+1]; b.z = tmp[i*4+2]; b.w = tmp[i*4+3];
        *reinterpret_cast<ushort4*>(p + i * 4) = b;
      }
    }
    __syncthreads();
    bf16x8 af[4], bfr[4];
    const int kq  = (lane >> 4) << 3;
    const int r16 = lane & 15;
#pragma unroll
    for (int m = 0; m < 4; ++m)
      af[m] = *reinterpret_cast<const bf16x8*>(&Al[(wr*64 + m*16 + r16) * LDT + kq]);
#pragma unroll
    for (int n = 0; n < 4; ++n)
      bfr[n] = *reinterpret_cast<const bf16x8*>(&Bl[(wc*64 + n*16 + r16) * LDT + kq]);
#pragma unroll
    for (int m = 0; m < 4; ++m)
#pragma unroll
      for (int n = 0; n < 4; ++n)
        acc[m][n] = __builtin_amdgcn_mfma_f32_16x16x32_bf16(af[m], bfr[n], acc[m][n], 0, 0, 0);
    __syncthreads();
  }
  const int col0 = n0 + wc * 64 + (lane & 15);
  const int rbs  = m0 + wr * 64 + ((lane >> 4) << 2);
#pragma unroll
  for (int m = 0; m < 4; ++m) {
#pragma unroll
    for (int r = 0; r < 4; ++r) {
      int row = rbs + m * 16 + r;
      if (MODE == 0) {
#pragma unroll
        for (int n = 0; n < 4; ++n) {
          float v = acc[m][n][r];
          v = v / (1.f + expf(-v));
          C[(size_t)row * N_ + col0 + n * 16] = v;
        }
      } else {
        float w = combine[(size_t)row * Ee + expert];
        if (first) {
#pragma unroll
          for (int n = 0; n < 4; ++n)
            C[(size_t)row * N_ + col0 + n * 16] = w * acc[m][n][r];
        } else {
#pragma unroll
          for (int n = 0; n < 4; ++n)
            C[(size_t)row * N_ + col0 + n * 16] += w * acc[m][n][r];
        }
      }
    }
  }
}

extern "C" void kernel_launch(void* const* d_in, const int* in_sizes, int n_in,
                              void* d_out, int out_size, void* d_ws, size_t ws_size,
                              hipStream_t stream)
{
  const float* x  = (const float*)d_in[0];   // [2,2048,1024]
  const float* gw = (const float*)d_in[1];   // [8,1024]
  const float* w1 = (const float*)d_in[2];   // [8,1024,2048]
  const float* w2 = (const float*)d_in[3];   // [8,2048,1024]
  float* out    = (float*)d_out;
  float* logits = out + (size_t)Tt * Dd;

  int*   meta = (int*)d_ws;                       // 64 ints
  int*   list = (int*)((char*)d_ws + 256);        // 8192 ints
  float* wgt  = (float*)((char*)d_ws + 256 + 32768);
  u16*   xb   = (u16*)((char*)d_ws + 262144);                         // 8 MB
  u16*   h1   = (u16*)((char*)d_ws + 262144 + 8388608);               // 32 MB
  u16*   wA   = (u16*)((char*)d_ws + 262144 + 8388608 + 33554432);    // 33.5 MB (w1T)
  u16*   wB   = (u16*)((char*)d_ws + 262144 + 8388608 + 2*33554432ull); // 33.5 MB (w2T, layout A)
  const size_t NEED_B = 262144ull + 8388608ull + 33554432ull + 33554432ull;
  const size_t NEED_A = NEED_B + 33554432ull;

  if (ws_size >= NEED_B) {
    fuse1_kernel<<<5120, 256, 0, stream>>>(x, gw, logits, xb, w1, wA);
    hipMemsetAsync(out, 0, (size_t)Tt * Dd * sizeof(float), stream);
    build_kernel<<<1, 256, 0, stream>>>(logits, meta, list, wgt);
    if (ws_size >= NEED_A) {
      fuse2_kernel<<<8192, 256, 0, stream>>>(xb, wA, h1, meta, list, wgt, w2, wB);
      gemm_g<1, Dd, Ff, 2><<<dim3(Dd/128, 32, 16), 256, 0, stream>>>(h1, wB, out, meta, list, wgt);
    } else {
      gemm_g<0, Ff, Dd, 1><<<dim3(Ff/128, 32, 8), 256, 0, stream>>>(xb, wA, h1, meta, list, wgt);
      transpose_bf16_kernel<<<dim3(Dd/64, Ff/64, Ee), 256, 0, stream>>>(w2, wA, Ff, Dd);
      gemm_g<1, Dd, Ff, 2><<<dim3(Dd/128, 32, 16), 256, 0, stream>>>(h1, wA, out, meta, list, wgt);
    }
  } else {
    float* combine = (float*)d_ws;
    float* h1d     = combine + (size_t)Tt * Ee;
    router_kernel<<<Tt / 4, 256, 0, stream>>>(x, gw, logits, nullptr);
    combine_kernel<<<Tt / 256, 256, 0, stream>>>(logits, combine);
    size_t cb = (size_t)Tt * Ee * sizeof(float);
    size_t avail = ws_size > cb ? (ws_size - cb) : 0;
    long maxrows = (long)(avail / ((size_t)Ff * sizeof(float)));
    int chunk = (maxrows >= Tt) ? Tt : (int)((maxrows / 128) * 128);
    if (chunk < 128) chunk = 128;
    for (int c0 = 0; c0 < Tt; c0 += chunk) {
      int rows = (Tt - c0) < chunk ? (Tt - c0) : chunk;
      for (int e = 0; e < Ee; ++e) {
        gemm_dense<0, Ff, Dd><<<dim3(Ff/128, rows/128), 256, 0, stream>>>(
            x + (size_t)c0 * Dd, w1 + (size_t)e * Dd * Ff, h1d, nullptr, e, 0);
        gemm_dense<1, Dd, Ff><<<dim3(Dd/128, rows/128), 256, 0, stream>>>(
            h1d, w2 + (size_t)e * Ff * Dd, out + (size_t)c0 * Dd,
            combine + (size_t)c0 * Ee, e, (e == 0) ? 1 : 0);
      }
    }
  }
}

// Round 16
// 188.552 us; speedup vs baseline: 1.1682x; 1.1682x over previous
//
#include <hip/hip_runtime.h>
#include <hip/hip_bf16.h>
#include <math.h>

#define Tt 4096
#define Dd 1024
#define Ff 2048
#define Ee 8

typedef unsigned short u16;
typedef short bf16x8 __attribute__((ext_vector_type(8)));
typedef float f32x4 __attribute__((ext_vector_type(4)));

__device__ __forceinline__ u16 f2bf(float f) {
  union { float f; unsigned u; } v; v.f = f;
  unsigned r = v.u + 0x7fffu + ((v.u >> 16) & 1u);
  return (u16)(r >> 16);
}

// async global->LDS, 16B per lane; LDS dest = wave-uniform base + lane*16
__device__ __forceinline__ void gload16(const void* g, void* l) {
  __builtin_amdgcn_global_load_lds(
      (const __attribute__((address_space(1))) unsigned int*)g,
      (__attribute__((address_space(3))) unsigned int*)l, 16, 0, 0);
}

// ---------------- shared device pieces ----------------
__device__ __forceinline__ void router_body(
    int t, int tid, const float* __restrict__ x, const float* __restrict__ gw,
    float* __restrict__ logits, u16* __restrict__ xb)
{
  int lane = tid & 63;
  const float* xr = x + (size_t)t * Dd;
  float xv[16];
#pragma unroll
  for (int i = 0; i < 4; ++i) {
    float4 v = *reinterpret_cast<const float4*>(xr + lane * 16 + i * 4);
    xv[i*4+0] = v.x; xv[i*4+1] = v.y; xv[i*4+2] = v.z; xv[i*4+3] = v.w;
  }
  if (xb) {
#pragma unroll
    for (int i = 0; i < 4; ++i) {
      ushort4 b;
      b.x = f2bf(xv[i*4+0]); b.y = f2bf(xv[i*4+1]);
      b.z = f2bf(xv[i*4+2]); b.w = f2bf(xv[i*4+3]);
      *reinterpret_cast<ushort4*>(xb + (size_t)t * Dd + lane * 16 + i * 4) = b;
    }
  }
#pragma unroll
  for (int e = 0; e < Ee; ++e) {
    const float* gr = gw + (size_t)e * Dd + lane * 16;
    float s = 0.f;
#pragma unroll
    for (int i = 0; i < 4; ++i) {
      float4 g = *reinterpret_cast<const float4*>(gr + i * 4);
      s += xv[i*4+0]*g.x + xv[i*4+1]*g.y + xv[i*4+2]*g.z + xv[i*4+3]*g.w;
    }
#pragma unroll
    for (int o = 32; o > 0; o >>= 1) s += __shfl_xor(s, o);
    if (lane == 0) logits[(size_t)t * Ee + e] = s;
  }
}

__device__ __forceinline__ void top2_of(
    const float* __restrict__ logits, int t, int& i1, int& i2, float& wa)
{
  float4 lo = *reinterpret_cast<const float4*>(logits + (size_t)t * 8);
  float4 hi = *reinterpret_cast<const float4*>(logits + (size_t)t * 8 + 4);
  float s[8] = {lo.x, lo.y, lo.z, lo.w, hi.x, hi.y, hi.z, hi.w};
  i1 = 0; float m1 = s[0];
#pragma unroll
  for (int e = 1; e < 8; ++e) if (s[e] > m1) { m1 = s[e]; i1 = e; }
  i2 = -1; float m2 = -__builtin_inff();
#pragma unroll
  for (int e = 0; e < 8; ++e) if (e != i1 && s[e] > m2) { m2 = s[e]; i2 = e; }
  wa = 1.f / (1.f + expf(m2 - m1));   // renormalized top-2 softmax weight of i1
}

__device__ __forceinline__ void transpose_tile(
    const float* __restrict__ ip, u16* __restrict__ op, int R, int C,
    int r0, int c0, int tid, u16 st[][65])
{
  int rr = tid >> 2;
  int cb = (tid & 3) * 16;
#pragma unroll
  for (int i = 0; i < 4; ++i) {
    float4 v = *reinterpret_cast<const float4*>(ip + (size_t)(r0 + rr) * C + c0 + cb + i * 4);
    st[rr][cb + i*4 + 0] = f2bf(v.x);
    st[rr][cb + i*4 + 1] = f2bf(v.y);
    st[rr][cb + i*4 + 2] = f2bf(v.z);
    st[rr][cb + i*4 + 3] = f2bf(v.w);
  }
  __syncthreads();
#pragma unroll
  for (int i = 0; i < 4; ++i) {
    ushort4 b;
    b.x = st[cb + i*4 + 0][rr];
    b.y = st[cb + i*4 + 1][rr];
    b.z = st[cb + i*4 + 2][rr];
    b.w = st[cb + i*4 + 3][rr];
    *reinterpret_cast<ushort4*>(op + (size_t)(c0 + rr) * R + r0 + cb + i * 4) = b;
  }
}

// r10 GEMM body: 128x128 tile, 4 waves, 3-buffer counted-vmcnt pipeline,
// piece-slot XOR swizzle (0 bank conflicts), expert-pinned XCD chunking.
// MODE 0: h1[slot] = silu(xb[list[slot]] @ w1T[e]^T)
// MODE 1: out[list[slot]] += wgt[slot]*(h1[slot] @ w2T[e]^T)  (atomicAdd)
template<int MODE, int N_, int K_>
__device__ __forceinline__ void gemm_body(
    int orig, u16* __restrict__ Al, u16* __restrict__ Bl,
    const u16* __restrict__ Abase, const u16* __restrict__ Bbase,
    void* __restrict__ Cout, const int* __restrict__ meta,
    const int* __restrict__ list, const float* __restrict__ wgt)
{
  constexpr int NXc = N_ / 128;
  constexpr int NYc = 32;               // covers worst-case cnt=4096
  constexpr int CPX = NXc * NYc;
  constexpr int ABUF = 128 * 32;        // u16 per buffer (8 KB)
  constexpr int NT  = K_ / 32;

  const int swz  = (orig & 7) * CPX + (orig >> 3);
  const int bz   = swz / CPX;
  const int rem  = swz - bz * CPX;
  const int by   = rem / NXc;
  const int bx   = rem - by * NXc;

  const int e   = bz;
  const int cnt = meta[e];
  if (by * 128 >= cnt) return;
  const int off = meta[32 + e];

  const int tid  = threadIdx.x;
  const int lane = tid & 63;
  const int wave = tid >> 6;
  const int wr   = wave >> 1, wc = wave & 1;
  const int n0   = bx * 128;

  const int l4 = lane >> 2;
  const int kp = (((lane & 3) ^ ((lane >> 3) & 3))) * 8;   // swizzled k-piece (shorts)

  const u16* aptr[2];
  int aoff[2];
#pragma unroll
  for (int c = 0; c < 2; ++c) {
    int chunk = wave * 2 + c;
    int row = chunk * 16 + l4;
    int i = by * 128 + row;
    if (i >= cnt) i = cnt - 1;          // clamp tail (dup rows; epilogue guards)
    int srow = (MODE == 0) ? list[off + i] : (off + i);
    aptr[c] = Abase + (size_t)srow * K_ + kp;
    aoff[c] = chunk * 512;
  }
  const u16* bptr[2];
  int boff[2];
#pragma unroll
  for (int c = 0; c < 2; ++c) {
    int chunk = wave * 2 + c;
    int row = chunk * 16 + l4;
    bptr[c] = Bbase + ((size_t)e * N_ + n0 + row) * K_ + kp;
    boff[c] = chunk * 512;
  }

  f32x4 acc[4][4] = {};
  const int r16 = lane & 15;
  const int kqs = (((lane >> 4) ^ ((lane >> 1) & 3))) * 8; // swizzled read slot

  u16 *a0 = Al, *a1 = Al + ABUF, *a2 = Al + 2 * ABUF;
  u16 *b0 = Bl, *b1 = Bl + ABUF, *b2 = Bl + 2 * ABUF;

  // prologue: stage tile 0 -> buf0, tile 1 -> buf1 (8 loads in flight per wave)
#pragma unroll
  for (int c = 0; c < 2; ++c) { gload16(aptr[c], a0 + aoff[c]); gload16(bptr[c], b0 + boff[c]); }
#pragma unroll
  for (int c = 0; c < 2; ++c) { gload16(aptr[c] + 32, a1 + aoff[c]); gload16(bptr[c] + 32, b1 + boff[c]); }

  for (int t = 0; t < NT; ++t) {
    if (t + 1 < NT) asm volatile("s_waitcnt vmcnt(4)" ::: "memory");
    else            asm volatile("s_waitcnt vmcnt(0)" ::: "memory");
    __builtin_amdgcn_s_barrier();           // tile t visible to all waves

    if (t + 2 < NT) {                       // prefetch t+2 into the spare buffer
      int k0 = (t + 2) * 32;
#pragma unroll
      for (int c = 0; c < 2; ++c) { gload16(aptr[c] + k0, a2 + aoff[c]); gload16(bptr[c] + k0, b2 + boff[c]); }
    }

    bf16x8 af[4], bfv[4];
#pragma unroll
    for (int m = 0; m < 4; ++m)
      af[m] = *reinterpret_cast<const bf16x8*>(&a0[(wr*64 + m*16 + r16) * 32 + kqs]);
#pragma unroll
    for (int n = 0; n < 4; ++n)
      bfv[n] = *reinterpret_cast<const bf16x8*>(&b0[(wc*64 + n*16 + r16) * 32 + kqs]);
    __builtin_amdgcn_s_setprio(1);
#pragma unroll
    for (int m = 0; m < 4; ++m)
#pragma unroll
      for (int n = 0; n < 4; ++n)
        acc[m][n] = __builtin_amdgcn_mfma_f32_16x16x32_bf16(af[m], bfv[n], acc[m][n], 0, 0, 0);
    __builtin_amdgcn_s_setprio(0);

    u16* ta = a0; a0 = a1; a1 = a2; a2 = ta;   // rotate buffers
    u16* tb = b0; b0 = b1; b1 = b2; b2 = tb;
  }

  // epilogue: C/D frag layout col=lane&15, row=(lane>>4)*4+reg
  const int colb = n0 + wc * 64 + r16;
  const int rb4  = wr * 64 + ((lane >> 4) << 2);
#pragma unroll
  for (int m = 0; m < 4; ++m) {
#pragma unroll
    for (int r = 0; r < 4; ++r) {
      int i = by * 128 + rb4 + m * 16 + r;
      if (i >= cnt) continue;
      if (MODE == 0) {
        u16* hp = (u16*)Cout + (size_t)(off + i) * N_;
#pragma unroll
        for (int n = 0; n < 4; ++n) {
          float v = acc[m][n][r];
          v = v / (1.f + expf(-v));            // silu
          hp[colb + n * 16] = f2bf(v);
        }
      } else {
        int   tok = list[off + i];
        float w   = wgt[off + i];
        float* o = (float*)Cout + (size_t)tok * N_;
#pragma unroll
        for (int n = 0; n < 4; ++n)
          atomicAdd(&o[colb + n * 16], w * acc[m][n][r]);
      }
    }
  }
}

// ---------------- standalone kernels ----------------
__global__ __launch_bounds__(256) void router_kernel(
    const float* __restrict__ x, const float* __restrict__ gw,
    float* __restrict__ logits, u16* __restrict__ xb)
{
  router_body(blockIdx.x * 4 + (threadIdx.x >> 6), threadIdx.x, x, gw, logits, xb);
}

// FUSE1: blocks [0,4096) transpose w1 -> w1T (expert-pinned);
//        blocks [4096,5120) router (logits + xb);
//        blocks [5120,5376) zero out[Tt*Dd] (replaces serialized memset).
__global__ __launch_bounds__(256) void fuse1_kernel(
    const float* __restrict__ x, const float* __restrict__ gw,
    float* __restrict__ logits, u16* __restrict__ xb,
    const float* __restrict__ w1, u16* __restrict__ w1T,
    float* __restrict__ outz)
{
  __shared__ u16 st[64][65];
  const int orig = blockIdx.x;
  if (orig < 4096) {
    int swz = (orig & 7) * 512 + (orig >> 3);
    int e   = swz / 512;                   // expert e -> XCD e (matches GEMM pinning)
    int rem = swz - e * 512;
    int by  = rem / 32, bx = rem - (rem / 32) * 32;
    const size_t eo = (size_t)e * Dd * Ff;
    transpose_tile(w1 + eo, w1T + eo, Dd, Ff, by * 64, bx * 64, threadIdx.x, st);
  } else if (orig < 5120) {
    router_body((orig - 4096) * 4 + (threadIdx.x >> 6), threadIdx.x, x, gw, logits, xb);
  } else {
    // zero out: 256 blocks x 256 thr x 16 float4 = Tt*Dd floats
    int z = orig - 5120;
    float4 zero = make_float4(0.f, 0.f, 0.f, 0.f);
    float4* p = reinterpret_cast<float4*>(outz);
#pragma unroll
    for (int i = 0; i < 16; ++i)
      p[(size_t)z * 4096 + i * 256 + threadIdx.x] = zero;
  }
}

// FUSE2: blocks [0,4096) = up-proj GEMM (reads w1T); blocks [4096,8192) =
// transpose w2 -> w2T (separate buffer). 48KB LDS pool shared.
__global__ __launch_bounds__(256) void fuse2_kernel(
    const u16* __restrict__ Abase, const u16* __restrict__ Bbase,
    void* __restrict__ Cout, const int* __restrict__ meta,
    const int* __restrict__ list, const float* __restrict__ wgt,
    const float* __restrict__ w2, u16* __restrict__ w2T)
{
  constexpr int ABUF = 128 * 32;
  __shared__ u16 pool[6 * ABUF];           // 48 KB
  const int orig = blockIdx.x;
  if (orig < 4096) {
    gemm_body<0, Ff, Dd>(orig, pool, pool + 3 * ABUF, Abase, Bbase, Cout, meta, list, wgt);
  } else {
    int og  = orig - 4096;
    int swz = (og & 7) * 512 + (og >> 3);
    int e   = swz / 512;
    int rem = swz - e * 512;
    int byy = rem / 16, bxx = rem - (rem / 16) * 16;
    const size_t eo = (size_t)e * Ff * Dd;
    transpose_tile(w2 + eo, w2T + eo, Ff, Dd, byy * 64, bxx * 64, threadIdx.x,
                   reinterpret_cast<u16(*)[65]>(pool));
  }
}

template<int MODE, int N_, int K_>
__global__ __launch_bounds__(256) void gemm_g(
    const u16* __restrict__ Abase, const u16* __restrict__ Bbase,
    void* __restrict__ Cout, const int* __restrict__ meta,
    const int* __restrict__ list, const float* __restrict__ wgt)
{
  constexpr int ABUF = 128 * 32;
  __shared__ u16 Al[3 * ABUF];
  __shared__ u16 Bl[3 * ABUF];
  const int orig = blockIdx.x + (N_ / 128) * (blockIdx.y + 32 * blockIdx.z);
  gemm_body<MODE, N_, K_>(orig, Al, Bl, Abase, Bbase, Cout, meta, list, wgt);
}

// transpose, serial path (layout B)
__global__ __launch_bounds__(256) void transpose_bf16_kernel(
    const float* __restrict__ in, u16* __restrict__ out, int R, int C)
{
  __shared__ u16 st[64][65];
  const size_t eoff = (size_t)blockIdx.z * R * C;
  transpose_tile(in + eoff, out + eoff, R, C, blockIdx.y * 64, blockIdx.x * 64,
                 threadIdx.x, st);
}

// ---------------- build, parallel 2-pass (8 blocks each) ----------------
// build1: block e counts tokens routed to expert e -> meta[e]
__global__ __launch_bounds__(256) void build1_kernel(
    const float* __restrict__ logits, int* __restrict__ meta)
{
  __shared__ int cnt;
  const int e = blockIdx.x;
  const int tid = threadIdx.x;
  if (tid == 0) cnt = 0;
  __syncthreads();
  int local = 0;
  for (int it = 0; it < Tt / 256; ++it) {
    int t = it * 256 + tid;
    int i1, i2; float wa;
    top2_of(logits, t, i1, i2, wa);
    if (i1 == e || i2 == e) ++local;
  }
  atomicAdd(&cnt, local);
  __syncthreads();
  if (tid == 0) meta[e] = cnt;
}

// build2: block e computes its offset from meta[0..7], assigns slots
__global__ __launch_bounds__(256) void build2_kernel(
    const float* __restrict__ logits, int* __restrict__ meta,
    int* __restrict__ list, float* __restrict__ wgt)
{
  __shared__ int cur;
  const int e = blockIdx.x;
  const int tid = threadIdx.x;
  int offv = 0;
  if (tid == 0) {
    for (int g = 0; g < Ee; ++g) { if (g < e) offv += meta[g]; }
    meta[32 + e] = offv;
    cur = 0;
  }
  __syncthreads();
  offv = meta[32 + e];
  for (int it = 0; it < Tt / 256; ++it) {
    int t = it * 256 + tid;
    int i1, i2; float wa;
    top2_of(logits, t, i1, i2, wa);
    float w = (i1 == e) ? wa : ((i2 == e) ? (1.f - wa) : 0.f);
    if (i1 == e || i2 == e) {
      int pos = atomicAdd(&cur, 1);
      list[offv + pos] = t;
      wgt[offv + pos] = w;
    }
  }
}

// ---------------- dense fallback (small-ws path) ----------------
__global__ __launch_bounds__(256) void combine_kernel(
    const float* __restrict__ logits, float* __restrict__ combine)
{
  int t = blockIdx.x * 256 + threadIdx.x;
  if (t >= Tt) return;
  int i1, i2; float wa;
  top2_of(logits, t, i1, i2, wa);
#pragma unroll
  for (int e = 0; e < 8; ++e)
    combine[(size_t)t * 8 + e] = (e == i1) ? wa : ((e == i2) ? (1.f - wa) : 0.f);
}

template<int MODE, int N_, int K_>
__global__ __launch_bounds__(256) void gemm_dense(
    const float* __restrict__ A, const float* __restrict__ Bg,
    float* __restrict__ C, const float* __restrict__ combine,
    int expert, int first)
{
  constexpr int BM = 128, BN = 128, BK = 32, LDT = 40;
  __shared__ u16 Al[BM * LDT];
  __shared__ u16 Bl[BN * LDT];
  const int tid  = threadIdx.x;
  const int lane = tid & 63;
  const int wave = tid >> 6;
  const int wr = wave >> 1, wc = wave & 1;
  const int m0 = blockIdx.y * BM;
  const int n0 = blockIdx.x * BN;
  f32x4 acc[4][4] = {};
  for (int k0 = 0; k0 < K_; k0 += BK) {
#pragma unroll
    for (int i = 0; i < 4; ++i) {
      int f = tid + 256 * i;
      int row = f >> 3;
      int c4 = (f & 7) << 2;
      float4 v = *reinterpret_cast<const float4*>(A + (size_t)(m0 + row) * K_ + k0 + c4);
      ushort4 b;
      b.x = f2bf(v.x); b.y = f2bf(v.y); b.z = f2bf(v.z); b.w = f2bf(v.w);
      *reinterpret_cast<ushort4*>(&Al[row * LDT + c4]) = b;
    }
    {
      int n  = tid & 127;
      int kb = (tid >> 7) << 4;
      const float* bp = Bg + (size_t)(k0 + kb) * N_ + n0 + n;
      u16 tmp[16];
#pragma unroll
      for (int kk = 0; kk < 16; ++kk)
        tmp[kk] = f2bf(bp[(size_t)kk * N_]);
      u16* p = &Bl[n * LDT + kb];
#pragma unroll
      for (int i = 0; i < 4; ++i) {
        ushort4 b;
        b.x = tmp[i*4+0]; b.y = tmp[i*4+1]; b.z = tmp[i*4+2]; b.w = tmp[i*4+3];
        *reinterpret_cast<ushort4*>(p + i * 4) = b;
      }
    }
    __syncthreads();
    bf16x8 af[4], bfr[4];
    const int kq  = (lane >> 4) << 3;
    const int r16 = lane & 15;
#pragma unroll
    for (int m = 0; m < 4; ++m)
      af[m] = *reinterpret_cast<const bf16x8*>(&Al[(wr*64 + m*16 + r16) * LDT + kq]);
#pragma unroll
    for (int n = 0; n < 4; ++n)
      bfr[n] = *reinterpret_cast<const bf16x8*>(&Bl[(wc*64 + n*16 + r16) * LDT + kq]);
#pragma unroll
    for (int m = 0; m < 4; ++m)
#pragma unroll
      for (int n = 0; n < 4; ++n)
        acc[m][n] = __builtin_amdgcn_mfma_f32_16x16x32_bf16(af[m], bfr[n], acc[m][n], 0, 0, 0);
    __syncthreads();
  }
  const int col0 = n0 + wc * 64 + (lane & 15);
  const int rbs  = m0 + wr * 64 + ((lane >> 4) << 2);
#pragma unroll
  for (int m = 0; m < 4; ++m) {
#pragma unroll
    for (int r = 0; r < 4; ++r) {
      int row = rbs + m * 16 + r;
      if (MODE == 0) {
#pragma unroll
        for (int n = 0; n < 4; ++n) {
          float v = acc[m][n][r];
          v = v / (1.f + expf(-v));
          C[(size_t)row * N_ + col0 + n * 16] = v;
        }
      } else {
        float w = combine[(size_t)row * Ee + expert];
        if (first) {
#pragma unroll
          for (int n = 0; n < 4; ++n)
            C[(size_t)row * N_ + col0 + n * 16] = w * acc[m][n][r];
        } else {
#pragma unroll
          for (int n = 0; n < 4; ++n)
            C[(size_t)row * N_ + col0 + n * 16] += w * acc[m][n][r];
        }
      }
    }
  }
}

extern "C" void kernel_launch(void* const* d_in, const int* in_sizes, int n_in,
                              void* d_out, int out_size, void* d_ws, size_t ws_size,
                              hipStream_t stream)
{
  const float* x  = (const float*)d_in[0];   // [2,2048,1024]
  const float* gw = (const float*)d_in[1];   // [8,1024]
  const float* w1 = (const float*)d_in[2];   // [8,1024,2048]
  const float* w2 = (const float*)d_in[3];   // [8,2048,1024]
  float* out    = (float*)d_out;
  float* logits = out + (size_t)Tt * Dd;

  int*   meta = (int*)d_ws;                       // 64 ints
  int*   list = (int*)((char*)d_ws + 256);        // 8192 ints
  float* wgt  = (float*)((char*)d_ws + 256 + 32768);
  u16*   xb   = (u16*)((char*)d_ws + 262144);                         // 8 MB
  u16*   h1   = (u16*)((char*)d_ws + 262144 + 8388608);               // 32 MB
  u16*   wA   = (u16*)((char*)d_ws + 262144 + 8388608 + 33554432);    // 33.5 MB (w1T)
  u16*   wB   = (u16*)((char*)d_ws + 262144 + 8388608 + 2*33554432ull); // 33.5 MB (w2T, layout A)
  const size_t NEED_B = 262144ull + 8388608ull + 33554432ull + 33554432ull;
  const size_t NEED_A = NEED_B + 33554432ull;

  if (ws_size >= NEED_B) {
    // router ∥ transpose-w1 ∥ zero-out in one dispatch (disjoint outputs)
    fuse1_kernel<<<5376, 256, 0, stream>>>(x, gw, logits, xb, w1, wA, out);
    build1_kernel<<<Ee, 256, 0, stream>>>(logits, meta);
    build2_kernel<<<Ee, 256, 0, stream>>>(logits, meta, list, wgt);
    if (ws_size >= NEED_A) {
      fuse2_kernel<<<8192, 256, 0, stream>>>(xb, wA, h1, meta, list, wgt, w2, wB);
      gemm_g<1, Dd, Ff><<<dim3(Dd/128, 32, 8), 256, 0, stream>>>(h1, wB, out, meta, list, wgt);
    } else {
      gemm_g<0, Ff, Dd><<<dim3(Ff/128, 32, 8), 256, 0, stream>>>(xb, wA, h1, meta, list, wgt);
      transpose_bf16_kernel<<<dim3(Dd/64, Ff/64, Ee), 256, 0, stream>>>(w2, wA, Ff, Dd);
      gemm_g<1, Dd, Ff><<<dim3(Dd/128, 32, 8), 256, 0, stream>>>(h1, wA, out, meta, list, wgt);
    }
  } else {
    float* combine = (float*)d_ws;
    float* h1d     = combine + (size_t)Tt * Ee;
    router_kernel<<<Tt / 4, 256, 0, stream>>>(x, gw, logits, nullptr);
    combine_kernel<<<Tt / 256, 256, 0, stream>>>(logits, combine);
    size_t cb = (size_t)Tt * Ee * sizeof(float);
    size_t avail = ws_size > cb ? (ws_size - cb) : 0;
    long maxrows = (long)(avail / ((size_t)Ff * sizeof(float)));
    int chunk = (maxrows >= Tt) ? Tt : (int)((maxrows / 128) * 128);
    if (chunk < 128) chunk = 128;
    for (int c0 = 0; c0 < Tt; c0 += chunk) {
      int rows = (Tt - c0) < chunk ? (Tt - c0) : chunk;
      for (int e = 0; e < Ee; ++e) {
        gemm_dense<0, Ff, Dd><<<dim3(Ff/128, rows/128), 256, 0, stream>>>(
            x + (size_t)c0 * Dd, w1 + (size_t)e * Dd * Ff, h1d, nullptr, e, 0);
        gemm_dense<1, Dd, Ff><<<dim3(Dd/128, rows/128), 256, 0, stream>>>(
            h1d, w2 + (size_t)e * Ff * Dd, out + (size_t)c0 * Dd,
            combine + (size_t)c0 * Ee, e, (e == 0) ? 1 : 0);
      }
    }
  }
}